// Round 13
// baseline (230.085 us; speedup 1.0000x reference)
//
#include <hip/hip_runtime.h>

typedef unsigned short u16;
typedef unsigned int u32;
typedef u16 u16x4 __attribute__((ext_vector_type(4)));
typedef u16 u16x8 __attribute__((ext_vector_type(8)));
typedef u32 u32x4 __attribute__((ext_vector_type(4)));
typedef float f32x4 __attribute__((ext_vector_type(4)));
typedef __bf16 bf16x8 __attribute__((ext_vector_type(8)));
typedef __bf16 bf16x2 __attribute__((ext_vector_type(2)));

#define DEV static __device__ __forceinline__

DEV float bf2f(u16 u) { u32 v = ((u32)u) << 16; float f; __builtin_memcpy(&f, &v, 4); return f; }
DEV u16 f2bf(float f) { u32 v; __builtin_memcpy(&v, &f, 4); v += 0x7fffu + ((v >> 16) & 1u); return (u16)(v >> 16); }
DEV bf16x8 ld_frag(const u16* p) { u16x8 v = *(const u16x8*)p; return __builtin_bit_cast(bf16x8, v); }

#define LOG10000 9.210340372f

// ------- merged weight transposes: 5 matrices in one launch, 3328 blocks -------
__global__ __launch_bounds__(256) void k_wtrans5(
    const float* __restrict__ Wqd, const float* __restrict__ Wqu, const float* __restrict__ Wkvd,
    const float* __restrict__ Wkvu, const float* __restrict__ Wo,
    u16* __restrict__ WqdT, u16* __restrict__ WquT, u16* __restrict__ WkvdT,
    u16* __restrict__ WkvuT, u16* __restrict__ WoT) {
  __shared__ float tile[32][33];
  int id = blockIdx.x;
  const float* in; u16* out; int R, C, Rp, bx, by;
  if (id < 256)       { in = Wqd;  out = WqdT;  R = 1024; C = 256;  Rp = 1024; bx = id & 7;  by = id >> 3; }
  else if (id < 1024) { id -= 256;  in = Wqu;  out = WquT;  R = 256;  C = 3072; Rp = 256;  bx = id % 96; by = id / 96; }
  else if (id < 1152) { id -= 1024; in = Wkvd; out = WkvdT; R = 1024; C = 80;   Rp = 1024; bx = id & 3;  by = id >> 2; }
  else if (id < 1280) { id -= 1152; in = Wkvu; out = WkvuT; R = 16;   C = 4096; Rp = 32;   bx = id;      by = 0; }
  else                { id -= 1280; in = Wo;   out = WoT;   R = 2048; C = 1024; Rp = 2048; bx = id & 31; by = id >> 5; }
  int c0 = bx * 32, r0 = by * 32;
  int tx = threadIdx.x & 31, ty = threadIdx.x >> 5;
#pragma unroll
  for (int p = 0; p < 4; p++) {
    int r = r0 + ty + p * 8, c = c0 + tx;
    tile[ty + p * 8][tx] = (r < R && c < C) ? in[(size_t)r * C + c] : 0.f;
  }
  __syncthreads();
#pragma unroll
  for (int p = 0; p < 4; p++)
    out[(size_t)(c0 + ty + p * 8) * Rp + r0 + tx] = f2bf(tile[tx][ty + p * 8]);
}

// ------- 64x64-tile GEMM body, A in f32 (cvt fused): C(M,N)f32 = A(M,K)f32 * Bt(N,K)bf16 -------
DEV void gemm64f_body(int m0, int n0, const float* __restrict__ A, const u16* __restrict__ Bt,
                      float* __restrict__ C, int N, int K, int tid, u16* As, u16* Bs) {
  constexpr int LSTR = 40;
  const int l = tid & 63, w = tid >> 6;
  const int wr = (w >> 1) * 32, wc = (w & 1) * 32;
  const int lr = l & 15, lk = (l >> 4) * 8;
  const int sr = tid >> 2, sc = (tid & 3) * 8;
  f32x4 acc[2][2] = {};
  const float* pa0 = A + (size_t)(m0 + sr) * K + sc;
  const u16* pb0 = Bt + (size_t)(n0 + sr) * K + sc;
  f32x4 vaa = *(const f32x4*)pa0, vab = *(const f32x4*)(pa0 + 4);
  u16x8 vb0 = *(const u16x8*)pb0;
  for (int k0 = 0; k0 < K; k0 += 32) {
    u16x8 va0 = { f2bf(vaa[0]), f2bf(vaa[1]), f2bf(vaa[2]), f2bf(vaa[3]),
                  f2bf(vab[0]), f2bf(vab[1]), f2bf(vab[2]), f2bf(vab[3]) };
    *(u16x8*)&As[sr * LSTR + sc] = va0;
    *(u16x8*)&Bs[sr * LSTR + sc] = vb0;
    __syncthreads();
    if (k0 + 32 < K) {
      vaa = *(const f32x4*)(pa0 + k0 + 32);
      vab = *(const f32x4*)(pa0 + k0 + 36);
      vb0 = *(const u16x8*)(pb0 + k0 + 32);
    }
    bf16x8 af[2], bf[2];
#pragma unroll
    for (int i = 0; i < 2; i++) af[i] = ld_frag(&As[(wr + i * 16 + lr) * LSTR + lk]);
#pragma unroll
    for (int j = 0; j < 2; j++) bf[j] = ld_frag(&Bs[(wc + j * 16 + lr) * LSTR + lk]);
#pragma unroll
    for (int i = 0; i < 2; i++)
#pragma unroll
      for (int j = 0; j < 2; j++)
        acc[i][j] = __builtin_amdgcn_mfma_f32_16x16x32_bf16(af[i], bf[j], acc[i][j], 0, 0, 0);
    __syncthreads();
  }
#pragma unroll
  for (int i = 0; i < 2; i++)
#pragma unroll
    for (int j = 0; j < 2; j++) {
      int row = m0 + wr + i * 16 + (l >> 4) * 4;
      int col = n0 + wc + j * 16 + lr;
#pragma unroll
      for (int r = 0; r < 4; r++)
        C[(size_t)(row + r) * N + col] = acc[i][j][r];
    }
}

// ------- merged down-projections: kv_down (128 blocks) + q_down (256 blocks) in one launch -------
__global__ __launch_bounds__(256) void k_downs(const float* __restrict__ q_in, const float* __restrict__ kv_in,
                                               const u16* __restrict__ WqdT, const u16* __restrict__ WkvdT,
                                               float* __restrict__ cq, float* __restrict__ ckvf) {
  __shared__ u16 As[64 * 40], Bs[64 * 40];
  int id = blockIdx.x, tid = threadIdx.x;
  if (id < 128) {
    int swzb = (id & 7) * 16 + (id >> 3);
    gemm64f_body((swzb >> 1) * 64, (swzb & 1) * 64, kv_in, WkvdT, ckvf, 128, 1024, tid, As, Bs);
  } else {
    int lin = id - 128;
    int swzb = (lin & 7) * 32 + (lin >> 3);
    gemm64f_body((swzb >> 2) * 64, (swzb & 3) * 64, q_in, WqdT, cq, 256, 1024, tid, As, Bs);
  }
}

// ------- merged norms: kv rms_norm(16)+rope (1024 blocks) + q rms_norm(256) (1024 blocks) -------
__global__ __launch_bounds__(256) void k_norms(const float* __restrict__ ckvf, const float* __restrict__ kvnw,
                                               const int* __restrict__ kpos, u16* __restrict__ ckvn,
                                               u16* __restrict__ kropeb,
                                               const float* __restrict__ cq, const float* __restrict__ qnw,
                                               u16* __restrict__ cqn, float scale) {
  int id = blockIdx.x, tid = threadIdx.x;
  int l = tid & 63;
  if (id < 1024) {
    int row = id * 4 + (tid >> 6);
    const float* x = ckvf + (size_t)row * 128;
    float v = (l < 16) ? x[l] : 0.f;
    float ss = v * v;
    ss += __shfl_xor(ss, 1); ss += __shfl_xor(ss, 2); ss += __shfl_xor(ss, 4); ss += __shfl_xor(ss, 8);
    if (l < 16) ckvn[(size_t)row * 32 + l] = f2bf(v * rsqrtf(ss * (1.f / 16.f) + 1e-7f) * kvnw[l]);
    if (l >= 16 && l < 32) ckvn[(size_t)row * 32 + l] = 0;
    if (l < 32) {
      float invf = __expf(-(LOG10000 / 32.f) * (float)l);
      float ang = (float)kpos[row] * invf;
      float c = cosf(ang), s = sinf(ang);
      float e = x[16 + 2 * l], o = x[17 + 2 * l];
      kropeb[(size_t)row * 64 + l]      = f2bf(e * c - o * s);
      kropeb[(size_t)row * 64 + l + 32] = f2bf(o * c + e * s);
    }
  } else {
    int row = (id - 1024) * 4 + (tid >> 6);
    const float* x = cq + (size_t)row * 256;
    f32x4 v = *(const f32x4*)(x + l * 4);
    float ss = v[0] * v[0] + v[1] * v[1] + v[2] * v[2] + v[3] * v[3];
#pragma unroll
    for (int m = 1; m < 64; m <<= 1) ss += __shfl_xor(ss, m);
    float rinv = rsqrtf(ss * (1.f / 256.f) + 1e-7f) * scale;
    const f32x4 wv = *(const f32x4*)(qnw + l * 4);
    u16x4 o = { f2bf(v[0] * rinv * wv[0]), f2bf(v[1] * rinv * wv[1]),
                f2bf(v[2] * rinv * wv[2]), f2bf(v[3] * rinv * wv[3]) };
    *(u16x4*)(cqn + (size_t)row * 256 + l * 4) = o;
  }
}

// ------- 128x128-tile GEMM body; MODE 0: bf16 C row-major, MODE 1: kv-split (Ckv + VT) -------
template <int MODE>
DEV void gemm128_body(int m0, int n0, const u16* __restrict__ A, const u16* __restrict__ Bt,
                      u16* __restrict__ C0, u16* __restrict__ C1, int N, int K, int tid,
                      u16* As, u16* Bs) {
  constexpr int LSTR = 40;
  const int l = tid & 63, w = tid >> 6;
  const int wr = (w >> 1) * 64, wc = (w & 1) * 64;
  const int lr = l & 15, lk = (l >> 4) * 8;
  const int sr = tid >> 2, sc = (tid & 3) * 8;
  f32x4 acc[4][4] = {};
  const u16* pa0 = A + (size_t)(m0 + sr) * K + sc;
  const u16* pa1 = A + (size_t)(m0 + 64 + sr) * K + sc;
  const u16* pb0 = Bt + (size_t)(n0 + sr) * K + sc;
  const u16* pb1 = Bt + (size_t)(n0 + 64 + sr) * K + sc;
  u16x8 va0 = *(const u16x8*)pa0, va1 = *(const u16x8*)pa1;
  u16x8 vb0 = *(const u16x8*)pb0, vb1 = *(const u16x8*)pb1;
  for (int k0 = 0; k0 < K; k0 += 32) {
    *(u16x8*)&As[sr * LSTR + sc] = va0;
    *(u16x8*)&As[(64 + sr) * LSTR + sc] = va1;
    *(u16x8*)&Bs[sr * LSTR + sc] = vb0;
    *(u16x8*)&Bs[(64 + sr) * LSTR + sc] = vb1;
    __syncthreads();
    if (k0 + 32 < K) {
      va0 = *(const u16x8*)(pa0 + k0 + 32);
      va1 = *(const u16x8*)(pa1 + k0 + 32);
      vb0 = *(const u16x8*)(pb0 + k0 + 32);
      vb1 = *(const u16x8*)(pb1 + k0 + 32);
    }
    bf16x8 af[4], bf[4];
#pragma unroll
    for (int i = 0; i < 4; i++) af[i] = ld_frag(&As[(wr + i * 16 + lr) * LSTR + lk]);
#pragma unroll
    for (int j = 0; j < 4; j++) bf[j] = ld_frag(&Bs[(wc + j * 16 + lr) * LSTR + lk]);
#pragma unroll
    for (int i = 0; i < 4; i++)
#pragma unroll
      for (int j = 0; j < 4; j++)
        acc[i][j] = __builtin_amdgcn_mfma_f32_16x16x32_bf16(af[i], bf[j], acc[i][j], 0, 0, 0);
    __syncthreads();
  }
  if (MODE == 0 || (n0 & 255) < 128) {
#pragma unroll
    for (int i = 0; i < 4; i++)
#pragma unroll
      for (int j = 0; j < 4; j++) {
        int row = m0 + wr + i * 16 + (l >> 4) * 4;
        int col = n0 + wc + j * 16 + lr;
#pragma unroll
        for (int r = 0; r < 4; r++)
          C0[(size_t)(row + r) * N + col] = f2bf(acc[i][j][r]);
      }
  } else {
#pragma unroll
    for (int i = 0; i < 4; i++)
#pragma unroll
      for (int j = 0; j < 4; j++) {
        int row = m0 + wr + i * 16 + (l >> 4) * 4;
        int col = n0 + wc + j * 16 + lr;
        int bb = row >> 11, srow = row & 2047;
        int hh2 = col >> 8, d = col & 127;
        u16x4 pk = { f2bf(acc[i][j][0]), f2bf(acc[i][j][1]),
                     f2bf(acc[i][j][2]), f2bf(acc[i][j][3]) };
        *(u16x4*)&C1[((size_t)(bb * 16 + hh2) * 128 + d) * 2048 + srow] = pk;
      }
  }
}

// ------- merged up-projections: kv_up (1024 blocks, K->Ckv V->VT) + q_up (768 blocks) -------
__global__ __launch_bounds__(256) void k_ups(const u16* __restrict__ ckvn, const u16* __restrict__ WkvuT,
                                             u16* __restrict__ Ckv, u16* __restrict__ VTb,
                                             const u16* __restrict__ cqn, const u16* __restrict__ WquT,
                                             u16* __restrict__ qproj) {
  __shared__ u16 As[128 * 40], Bs[128 * 40];
  int id = blockIdx.x, tid = threadIdx.x;
  if (id < 1024) {
    int swzb = (id & 7) * 128 + (id >> 3);
    gemm128_body<1>((swzb >> 5) * 128, (swzb & 31) * 128, ckvn, WkvuT, Ckv, VTb, 4096, 32, tid, As, Bs);
  } else {
    int lin = id - 1024;
    int swzb = (lin & 7) * 96 + (lin >> 3);
    gemm128_body<0>((swzb / 24) * 128, (swzb % 24) * 128, cqn, WquT, qproj, nullptr, 3072, 256, tid, As, Bs);
  }
}

// ---------------- GEMM 64(M)x128(N) tile, f32 out (out-projection) ----------------
__global__ __launch_bounds__(256) void k_gemmh(const u16* __restrict__ A, const u16* __restrict__ Bt,
                                               float* __restrict__ Cv, int M, int N, int K) {
  constexpr int LSTR = 40;
  __shared__ u16 As[64 * LSTR], Bs[128 * LSTR];
  const int tid = threadIdx.x, l = tid & 63, w = tid >> 6;
  const int nwg = gridDim.x * gridDim.y;
  const int lin = blockIdx.y * gridDim.x + blockIdx.x;
  const int swzb = (lin & 7) * (nwg >> 3) + (lin >> 3);
  const int m0 = (swzb / gridDim.x) * 64, n0 = (swzb % gridDim.x) * 128;
  const int wr = (w >> 1) * 32, wc = (w & 1) * 64;
  const int lr = l & 15, lk = (l >> 4) * 8;
  const int sr = tid >> 2, sc = (tid & 3) * 8;
  f32x4 acc[2][4] = {};
  const u16* pa0 = A + (size_t)(m0 + sr) * K + sc;
  const u16* pb0 = Bt + (size_t)(n0 + sr) * K + sc;
  const u16* pb1 = Bt + (size_t)(n0 + 64 + sr) * K + sc;
  u16x8 va0 = *(const u16x8*)pa0;
  u16x8 vb0 = *(const u16x8*)pb0, vb1 = *(const u16x8*)pb1;
  for (int k0 = 0; k0 < K; k0 += 32) {
    *(u16x8*)&As[sr * LSTR + sc] = va0;
    *(u16x8*)&Bs[sr * LSTR + sc] = vb0;
    *(u16x8*)&Bs[(64 + sr) * LSTR + sc] = vb1;
    __syncthreads();
    if (k0 + 32 < K) {
      va0 = *(const u16x8*)(pa0 + k0 + 32);
      vb0 = *(const u16x8*)(pb0 + k0 + 32);
      vb1 = *(const u16x8*)(pb1 + k0 + 32);
    }
    bf16x8 af[2], bf[4];
#pragma unroll
    for (int i = 0; i < 2; i++) af[i] = ld_frag(&As[(wr + i * 16 + lr) * LSTR + lk]);
#pragma unroll
    for (int j = 0; j < 4; j++) bf[j] = ld_frag(&Bs[(wc + j * 16 + lr) * LSTR + lk]);
#pragma unroll
    for (int i = 0; i < 2; i++)
#pragma unroll
      for (int j = 0; j < 4; j++)
        acc[i][j] = __builtin_amdgcn_mfma_f32_16x16x32_bf16(af[i], bf[j], acc[i][j], 0, 0, 0);
    __syncthreads();
  }
#pragma unroll
  for (int i = 0; i < 2; i++)
#pragma unroll
    for (int j = 0; j < 4; j++) {
      int row = m0 + wr + i * 16 + (l >> 4) * 4;
      int col = n0 + wc + j * 16 + lr;
#pragma unroll
      for (int r = 0; r < 4; r++)
        Cv[(size_t)(row + r) * N + col] = acc[i][j][r];
    }
}

// ---- fused attention v13: KVBLK=128 (16 tiles, 80KB LDS), fused Q-rope, in-reg P ----
__global__ __launch_bounds__(512, 2) void k_attn(const u16* __restrict__ Qp, const u16* __restrict__ Ckv,
                                                 const u16* __restrict__ kropeb, const u16* __restrict__ VT,
                                                 const int* __restrict__ qpos, u16* __restrict__ AO) {
  __shared__ u16 Ks[128 * 192];  // 48KB, XOR-swizzled
  __shared__ u16 Vs[128 * 128];  // 32KB, d-major (s-width 128), XOR-swizzled
  const int tid = threadIdx.x, l = tid & 63, w = tid >> 6;
  const int lr = l & 15, g = l >> 4, lk = g * 8;
  const int bid = blockIdx.x, bh = bid & 31, qt = bid >> 5;  // bh%8 fixes XCD for K/V L2 reuse
  const int b = bh >> 4, hh = bh & 15;
  const int m0 = qt * 128;
  const u32 swz = (u32)(lr & 7) << 3;

  // Q fragments (B-operand) with FUSED ROPE: wave w owns q-rows m0 + w*16 .. +15
  bf16x8 qa[6];
  {
    const int rowi = b * 2048 + m0 + w * 16 + lr;
    const u16* qrow = Qp + (size_t)rowi * 3072 + hh * 192;
#pragma unroll
    for (int kk = 0; kk < 4; kk++) qa[kk] = ld_frag(qrow + kk * 32 + lk);
    // rope: reshaped dims (128+8g+i, 160+8g+i) <- orig dims 128+16g+2i, +2i+1 (all in-lane)
    u16x8 e0 = *(const u16x8*)(qrow + 128 + 16 * g);
    u16x8 e1 = *(const u16x8*)(qrow + 136 + 16 * g);
    float fpos = (float)qpos[rowi];
    u16x8 r4, r5;
#pragma unroll
    for (int i = 0; i < 8; i++) {
      float invf = __expf(-(LOG10000 / 32.f) * (float)(8 * g + i));
      float ang = fpos * invf;
      float c = cosf(ang), s = sinf(ang);
      float ev = bf2f(i < 4 ? e0[2 * i] : e1[2 * i - 8]);
      float od = bf2f(i < 4 ? e0[2 * i + 1] : e1[2 * i - 7]);
      r4[i] = f2bf(ev * c - od * s);
      r5[i] = f2bf(od * c + ev * s);
    }
    qa[4] = __builtin_bit_cast(bf16x8, r4);
    qa[5] = __builtin_bit_cast(bf16x8, r5);
  }

  // staging: K = 128x192 (6 chunks/thread @512), V = 128x128 d-major (4 chunks/thread)
  const u16* kptr[6]; int kstep[6]; u32 klds[6];
#pragma unroll
  for (int p = 0; p < 6; p++) {
    int c2 = tid + p * 512;
    int r = c2 / 24, cc = c2 - r * 24;
    klds[p] = (u32)(r * 192 + cc * 8) ^ ((u32)(r & 7) << 3);
    if (cc < 16) { kptr[p] = Ckv + ((size_t)(b * 2048 + r)) * 4096 + hh * 256 + cc * 8; kstep[p] = 128 * 4096; }
    else         { kptr[p] = kropeb + ((size_t)(b * 2048 + r)) * 64 + (cc - 16) * 8;    kstep[p] = 128 * 64; }
  }
  const u16* vptr[4]; u32 vlds[4];
#pragma unroll
  for (int p = 0; p < 4; p++) {
    int c2 = tid + p * 512;
    int d = c2 >> 4, cc = c2 & 15;
    vlds[p] = (u32)(d * 128 + cc * 8) ^ ((u32)(d & 7) << 3);
    vptr[p] = VT + ((size_t)bh * 128 + d) * 2048 + cc * 8;
  }
  u16x8 kreg[6], vreg[4];
#pragma unroll
  for (int p = 0; p < 6; p++) { kreg[p] = *(const u16x8*)kptr[p]; kptr[p] += kstep[p]; }
#pragma unroll
  for (int p = 0; p < 4; p++) { vreg[p] = *(const u16x8*)vptr[p]; vptr[p] += 128; }

  f32x4 oacc[8] = {};
  float lsum = 0.f;
  const int srcA = lr + ((l & 16) << 1);
  const int srcB = srcA + 16;
  const bool hi = (l & 32) != 0;

  for (int t = 0; t < 16; t++) {
    // write staged regs -> LDS (vmcnt wait auto-inserted)
#pragma unroll
    for (int p = 0; p < 6; p++) *(u16x8*)&Ks[klds[p]] = kreg[p];
#pragma unroll
    for (int p = 0; p < 4; p++) *(u16x8*)&Vs[vlds[p]] = vreg[p];
    __syncthreads();
    if (t + 1 < 16) {  // issue next-tile loads; latency hides under compute
#pragma unroll
      for (int p = 0; p < 6; p++) { kreg[p] = *(const u16x8*)kptr[p]; kptr[p] += kstep[p]; }
#pragma unroll
      for (int p = 0; p < 4; p++) { vreg[p] = *(const u16x8*)vptr[p]; vptr[p] += 128; }
    }
    u32 pw[8][2];
    // QK half A: kv rows 0..63 -> pw[0..3]
    {
      f32x4 sacc[4] = {};
      __builtin_amdgcn_s_setprio(1);
#pragma unroll
      for (int n = 0; n < 4; n++)
#pragma unroll
        for (int kk = 0; kk < 6; kk++)
          sacc[n] = __builtin_amdgcn_mfma_f32_16x16x32_bf16(
              ld_frag(&Ks[(u32)((n * 16 + lr) * 192 + kk * 32 + lk) ^ swz]), qa[kk], sacc[n], 0, 0, 0);
      __builtin_amdgcn_s_setprio(0);
#pragma unroll
      for (int n = 0; n < 4; n++) {
        float p0 = __expf(sacc[n][0]), p1 = __expf(sacc[n][1]),
              p2 = __expf(sacc[n][2]), p3 = __expf(sacc[n][3]);
        lsum += (p0 + p1) + (p2 + p3);
        bf16x2 a01 = { (__bf16)p0, (__bf16)p1 };
        bf16x2 a23 = { (__bf16)p2, (__bf16)p3 };
        pw[n][0] = __builtin_bit_cast(u32, a01);
        pw[n][1] = __builtin_bit_cast(u32, a23);
      }
    }
    // QK half B: kv rows 64..127 -> pw[4..7]
    {
      f32x4 sacc[4] = {};
      __builtin_amdgcn_s_setprio(1);
#pragma unroll
      for (int n = 0; n < 4; n++)
#pragma unroll
        for (int kk = 0; kk < 6; kk++)
          sacc[n] = __builtin_amdgcn_mfma_f32_16x16x32_bf16(
              ld_frag(&Ks[(u32)(((n + 4) * 16 + lr) * 192 + kk * 32 + lk) ^ swz]), qa[kk], sacc[n], 0, 0, 0);
      __builtin_amdgcn_s_setprio(0);
#pragma unroll
      for (int n = 0; n < 4; n++) {
        float p0 = __expf(sacc[n][0]), p1 = __expf(sacc[n][1]),
              p2 = __expf(sacc[n][2]), p3 = __expf(sacc[n][3]);
        lsum += (p0 + p1) + (p2 + p3);
        bf16x2 a01 = { (__bf16)p0, (__bf16)p1 };
        bf16x2 a23 = { (__bf16)p2, (__bf16)p3 };
        pw[n + 4][0] = __builtin_bit_cast(u32, a01);
        pw[n + 4][1] = __builtin_bit_cast(u32, a23);
      }
    }
    // PV over 4 kv-chunks of 32: redistribute pw -> A-frag, MFMA against Vs
    __builtin_amdgcn_s_setprio(1);
#pragma unroll
    for (int kk2 = 0; kk2 < 4; kk2++) {
      u32 t0a = __shfl(pw[2 * kk2][0], srcA), t1a = __shfl(pw[2 * kk2 + 1][0], srcA);
      u32 t0b = __shfl(pw[2 * kk2][1], srcA), t1b = __shfl(pw[2 * kk2 + 1][1], srcA);
      u32 t0c = __shfl(pw[2 * kk2][0], srcB), t1c = __shfl(pw[2 * kk2 + 1][0], srcB);
      u32 t0d = __shfl(pw[2 * kk2][1], srcB), t1d = __shfl(pw[2 * kk2 + 1][1], srcB);
      u32x4 pv = { hi ? t1a : t0a, hi ? t1b : t0b, hi ? t1c : t0c, hi ? t1d : t0d };
      bf16x8 paf = __builtin_bit_cast(bf16x8, pv);
#pragma unroll
      for (int n2 = 0; n2 < 8; n2++)
        oacc[n2] = __builtin_amdgcn_mfma_f32_16x16x32_bf16(
            paf, ld_frag(&Vs[(u32)((n2 * 16 + lr) * 128 + kk2 * 32 + lk) ^ swz]), oacc[n2], 0, 0, 0);
    }
    __builtin_amdgcn_s_setprio(0);
    __syncthreads();
  }
  // epilogue: lsum per q=lr; sum the 4 g-groups, redistribute to rows 4g+r
  float s = lsum;
  s += __shfl_xor(s, 16);
  s += __shfl_xor(s, 32);
  float rl = 1.f / s;
  float rlv[4];
#pragma unroll
  for (int r = 0; r < 4; r++) rlv[r] = __shfl(rl, g * 4 + r);
#pragma unroll
  for (int n2 = 0; n2 < 8; n2++)
#pragma unroll
    for (int r = 0; r < 4; r++) {
      int row = m0 + w * 16 + g * 4 + r;
      AO[((size_t)(b * 2048 + row) * 16 + hh) * 128 + n2 * 16 + lr] = f2bf(oacc[n2][r] * rlv[r]);
    }
}

extern "C" void kernel_launch(void* const* d_in, const int* in_sizes, int n_in,
                              void* d_out, int out_size, void* d_ws, size_t ws_size,
                              hipStream_t stream) {
  const float* q_in  = (const float*)d_in[0];
  const float* kv_in = (const float*)d_in[1];
  const int*   qpos  = (const int*)d_in[2];
  const int*   kpos  = (const int*)d_in[3];
  const float* Wqd   = (const float*)d_in[4];
  const float* qnw   = (const float*)d_in[5];
  const float* Wqu   = (const float*)d_in[6];
  const float* Wkvd  = (const float*)d_in[7];
  const float* kvnw  = (const float*)d_in[8];
  const float* Wkvu  = (const float*)d_in[9];
  const float* Wo    = (const float*)d_in[10];
  float* out = (float*)d_out;
  char* ws = (char*)d_ws;
  size_t off = 0;
  auto alloc = [&](size_t bytes) -> void* {
    void* p = ws + off; off += (bytes + 255) & ~(size_t)255; return p;
  };
  u16*   WqdT   = (u16*)alloc(256ull * 1024 * 2);
  u16*   WquT   = (u16*)alloc(3072ull * 256 * 2);
  u16*   WkvdT  = (u16*)alloc(128ull * 1024 * 2);
  u16*   WkvuT  = (u16*)alloc(4096ull * 32 * 2);
  u16*   WoT    = (u16*)alloc(1024ull * 2048 * 2);
  float* ckvf   = (float*)alloc(4096ull * 128 * 4);
  u16*   ckvn   = (u16*)alloc(4096ull * 32 * 2);
  u16*   kropeb = (u16*)alloc(4096ull * 64 * 2);
  u16*   Ckv    = (u16*)alloc(4096ull * 4096 * 2);
  u16*   VTb    = (u16*)alloc(32ull * 128 * 2048 * 2);
  float* cq     = (float*)alloc(4096ull * 256 * 4);
  u16*   cqn    = (u16*)alloc(4096ull * 256 * 2);
  u16*   qproj  = (u16*)alloc(4096ull * 3072 * 2);
  u16*   AOb    = (u16*)alloc(4096ull * 2048 * 2);
  (void)in_sizes; (void)n_in; (void)out_size; (void)ws_size;

  // 1: all 5 weight transposes
  k_wtrans5<<<3328, 256, 0, stream>>>(Wqd, Wqu, Wkvd, Wkvu, Wo, WqdT, WquT, WkvdT, WkvuT, WoT);
  // 2: both down-projections (f32-A, fused cvt)
  k_downs<<<384, 256, 0, stream>>>(q_in, kv_in, WqdT, WkvdT, cq, ckvf);
  // 3: both norms
  k_norms<<<2048, 256, 0, stream>>>(ckvf, kvnw, kpos, ckvn, kropeb, cq, qnw, cqn, 0.07216878364870322f);
  // 4: both up-projections (kv_up: K->Ckv + V->VT; q_up)
  k_ups<<<1792, 256, 0, stream>>>(ckvn, WkvuT, Ckv, VTb, cqn, WquT, qproj);
  // 5: attention (KVBLK=128, fused q-rope; k_qrope eliminated)
  k_attn<<<512, 512, 0, stream>>>(qproj, Ckv, kropeb, VTb, qpos, AOb);
  // 6: output projection
  k_gemmh<<<dim3(8, 64), 256, 0, stream>>>(AOb, WoT, out, 4096, 1024, 2048);
}

// Round 14
// 212.999 us; speedup vs baseline: 1.0802x; 1.0802x over previous
//
#include <hip/hip_runtime.h>

typedef unsigned short u16;
typedef unsigned int u32;
typedef u16 u16x4 __attribute__((ext_vector_type(4)));
typedef u16 u16x8 __attribute__((ext_vector_type(8)));
typedef u32 u32x4 __attribute__((ext_vector_type(4)));
typedef float f32x4 __attribute__((ext_vector_type(4)));
typedef __bf16 bf16x8 __attribute__((ext_vector_type(8)));
typedef __bf16 bf16x2 __attribute__((ext_vector_type(2)));

#define DEV static __device__ __forceinline__

DEV float bf2f(u16 u) { u32 v = ((u32)u) << 16; float f; __builtin_memcpy(&f, &v, 4); return f; }
DEV u16 f2bf(float f) { u32 v; __builtin_memcpy(&v, &f, 4); v += 0x7fffu + ((v >> 16) & 1u); return (u16)(v >> 16); }
DEV bf16x8 ld_frag(const u16* p) { u16x8 v = *(const u16x8*)p; return __builtin_bit_cast(bf16x8, v); }

#define LOG10000 9.210340372f

// ------- merged weight transposes: 5 matrices in one launch, 3328 blocks -------
__global__ __launch_bounds__(256) void k_wtrans5(
    const float* __restrict__ Wqd, const float* __restrict__ Wqu, const float* __restrict__ Wkvd,
    const float* __restrict__ Wkvu, const float* __restrict__ Wo,
    u16* __restrict__ WqdT, u16* __restrict__ WquT, u16* __restrict__ WkvdT,
    u16* __restrict__ WkvuT, u16* __restrict__ WoT) {
  __shared__ float tile[32][33];
  int id = blockIdx.x;
  const float* in; u16* out; int R, C, Rp, bx, by;
  if (id < 256)       { in = Wqd;  out = WqdT;  R = 1024; C = 256;  Rp = 1024; bx = id & 7;  by = id >> 3; }
  else if (id < 1024) { id -= 256;  in = Wqu;  out = WquT;  R = 256;  C = 3072; Rp = 256;  bx = id % 96; by = id / 96; }
  else if (id < 1152) { id -= 1024; in = Wkvd; out = WkvdT; R = 1024; C = 80;   Rp = 1024; bx = id & 3;  by = id >> 2; }
  else if (id < 1280) { id -= 1152; in = Wkvu; out = WkvuT; R = 16;   C = 4096; Rp = 32;   bx = id;      by = 0; }
  else                { id -= 1280; in = Wo;   out = WoT;   R = 2048; C = 1024; Rp = 2048; bx = id & 31; by = id >> 5; }
  int c0 = bx * 32, r0 = by * 32;
  int tx = threadIdx.x & 31, ty = threadIdx.x >> 5;
#pragma unroll
  for (int p = 0; p < 4; p++) {
    int r = r0 + ty + p * 8, c = c0 + tx;
    tile[ty + p * 8][tx] = (r < R && c < C) ? in[(size_t)r * C + c] : 0.f;
  }
  __syncthreads();
#pragma unroll
  for (int p = 0; p < 4; p++)
    out[(size_t)(c0 + ty + p * 8) * Rp + r0 + tx] = f2bf(tile[tx][ty + p * 8]);
}

// ------- 64x64-tile GEMM body, A in f32 (cvt fused): C(M,N)f32 = A(M,K)f32 * Bt(N,K)bf16 -------
DEV void gemm64f_body(int m0, int n0, const float* __restrict__ A, const u16* __restrict__ Bt,
                      float* __restrict__ C, int N, int K, int tid, u16* As, u16* Bs) {
  constexpr int LSTR = 40;
  const int l = tid & 63, w = tid >> 6;
  const int wr = (w >> 1) * 32, wc = (w & 1) * 32;
  const int lr = l & 15, lk = (l >> 4) * 8;
  const int sr = tid >> 2, sc = (tid & 3) * 8;
  f32x4 acc[2][2] = {};
  const float* pa0 = A + (size_t)(m0 + sr) * K + sc;
  const u16* pb0 = Bt + (size_t)(n0 + sr) * K + sc;
  f32x4 vaa = *(const f32x4*)pa0, vab = *(const f32x4*)(pa0 + 4);
  u16x8 vb0 = *(const u16x8*)pb0;
  for (int k0 = 0; k0 < K; k0 += 32) {
    u16x8 va0 = { f2bf(vaa[0]), f2bf(vaa[1]), f2bf(vaa[2]), f2bf(vaa[3]),
                  f2bf(vab[0]), f2bf(vab[1]), f2bf(vab[2]), f2bf(vab[3]) };
    *(u16x8*)&As[sr * LSTR + sc] = va0;
    *(u16x8*)&Bs[sr * LSTR + sc] = vb0;
    __syncthreads();
    if (k0 + 32 < K) {
      vaa = *(const f32x4*)(pa0 + k0 + 32);
      vab = *(const f32x4*)(pa0 + k0 + 36);
      vb0 = *(const u16x8*)(pb0 + k0 + 32);
    }
    bf16x8 af[2], bf[2];
#pragma unroll
    for (int i = 0; i < 2; i++) af[i] = ld_frag(&As[(wr + i * 16 + lr) * LSTR + lk]);
#pragma unroll
    for (int j = 0; j < 2; j++) bf[j] = ld_frag(&Bs[(wc + j * 16 + lr) * LSTR + lk]);
#pragma unroll
    for (int i = 0; i < 2; i++)
#pragma unroll
      for (int j = 0; j < 2; j++)
        acc[i][j] = __builtin_amdgcn_mfma_f32_16x16x32_bf16(af[i], bf[j], acc[i][j], 0, 0, 0);
    __syncthreads();
  }
#pragma unroll
  for (int i = 0; i < 2; i++)
#pragma unroll
    for (int j = 0; j < 2; j++) {
      int row = m0 + wr + i * 16 + (l >> 4) * 4;
      int col = n0 + wc + j * 16 + lr;
#pragma unroll
      for (int r = 0; r < 4; r++)
        C[(size_t)(row + r) * N + col] = acc[i][j][r];
    }
}

// ------- merged down-projections: kv_down (128 blocks) + q_down (256 blocks) in one launch -------
__global__ __launch_bounds__(256) void k_downs(const float* __restrict__ q_in, const float* __restrict__ kv_in,
                                               const u16* __restrict__ WqdT, const u16* __restrict__ WkvdT,
                                               float* __restrict__ cq, float* __restrict__ ckvf) {
  __shared__ u16 As[64 * 40], Bs[64 * 40];
  int id = blockIdx.x, tid = threadIdx.x;
  if (id < 128) {
    int swzb = (id & 7) * 16 + (id >> 3);
    gemm64f_body((swzb >> 1) * 64, (swzb & 1) * 64, kv_in, WkvdT, ckvf, 128, 1024, tid, As, Bs);
  } else {
    int lin = id - 128;
    int swzb = (lin & 7) * 32 + (lin >> 3);
    gemm64f_body((swzb >> 2) * 64, (swzb & 3) * 64, q_in, WqdT, cq, 256, 1024, tid, As, Bs);
  }
}

// ------- merged norms: kv rms_norm(16)+rope (1024 blocks) + q rms_norm(256) (1024 blocks) -------
__global__ __launch_bounds__(256) void k_norms(const float* __restrict__ ckvf, const float* __restrict__ kvnw,
                                               const int* __restrict__ kpos, u16* __restrict__ ckvn,
                                               u16* __restrict__ kropeb,
                                               const float* __restrict__ cq, const float* __restrict__ qnw,
                                               u16* __restrict__ cqn, float scale) {
  int id = blockIdx.x, tid = threadIdx.x;
  int l = tid & 63;
  if (id < 1024) {
    int row = id * 4 + (tid >> 6);
    const float* x = ckvf + (size_t)row * 128;
    float v = (l < 16) ? x[l] : 0.f;
    float ss = v * v;
    ss += __shfl_xor(ss, 1); ss += __shfl_xor(ss, 2); ss += __shfl_xor(ss, 4); ss += __shfl_xor(ss, 8);
    if (l < 16) ckvn[(size_t)row * 32 + l] = f2bf(v * rsqrtf(ss * (1.f / 16.f) + 1e-7f) * kvnw[l]);
    if (l >= 16 && l < 32) ckvn[(size_t)row * 32 + l] = 0;
    if (l < 32) {
      float invf = __expf(-(LOG10000 / 32.f) * (float)l);
      float ang = (float)kpos[row] * invf;
      float c = cosf(ang), s = sinf(ang);
      float e = x[16 + 2 * l], o = x[17 + 2 * l];
      kropeb[(size_t)row * 64 + l]      = f2bf(e * c - o * s);
      kropeb[(size_t)row * 64 + l + 32] = f2bf(o * c + e * s);
    }
  } else {
    int row = (id - 1024) * 4 + (tid >> 6);
    const float* x = cq + (size_t)row * 256;
    f32x4 v = *(const f32x4*)(x + l * 4);
    float ss = v[0] * v[0] + v[1] * v[1] + v[2] * v[2] + v[3] * v[3];
#pragma unroll
    for (int m = 1; m < 64; m <<= 1) ss += __shfl_xor(ss, m);
    float rinv = rsqrtf(ss * (1.f / 256.f) + 1e-7f) * scale;
    const f32x4 wv = *(const f32x4*)(qnw + l * 4);
    u16x4 o = { f2bf(v[0] * rinv * wv[0]), f2bf(v[1] * rinv * wv[1]),
                f2bf(v[2] * rinv * wv[2]), f2bf(v[3] * rinv * wv[3]) };
    *(u16x4*)(cqn + (size_t)row * 256 + l * 4) = o;
  }
}

// ------- 128x128-tile GEMM body; MODE 0: bf16 C row-major, MODE 1: kv-split (Ckv + VT) -------
template <int MODE>
DEV void gemm128_body(int m0, int n0, const u16* __restrict__ A, const u16* __restrict__ Bt,
                      u16* __restrict__ C0, u16* __restrict__ C1, int N, int K, int tid,
                      u16* As, u16* Bs) {
  constexpr int LSTR = 40;
  const int l = tid & 63, w = tid >> 6;
  const int wr = (w >> 1) * 64, wc = (w & 1) * 64;
  const int lr = l & 15, lk = (l >> 4) * 8;
  const int sr = tid >> 2, sc = (tid & 3) * 8;
  f32x4 acc[4][4] = {};
  const u16* pa0 = A + (size_t)(m0 + sr) * K + sc;
  const u16* pa1 = A + (size_t)(m0 + 64 + sr) * K + sc;
  const u16* pb0 = Bt + (size_t)(n0 + sr) * K + sc;
  const u16* pb1 = Bt + (size_t)(n0 + 64 + sr) * K + sc;
  u16x8 va0 = *(const u16x8*)pa0, va1 = *(const u16x8*)pa1;
  u16x8 vb0 = *(const u16x8*)pb0, vb1 = *(const u16x8*)pb1;
  for (int k0 = 0; k0 < K; k0 += 32) {
    *(u16x8*)&As[sr * LSTR + sc] = va0;
    *(u16x8*)&As[(64 + sr) * LSTR + sc] = va1;
    *(u16x8*)&Bs[sr * LSTR + sc] = vb0;
    *(u16x8*)&Bs[(64 + sr) * LSTR + sc] = vb1;
    __syncthreads();
    if (k0 + 32 < K) {
      va0 = *(const u16x8*)(pa0 + k0 + 32);
      va1 = *(const u16x8*)(pa1 + k0 + 32);
      vb0 = *(const u16x8*)(pb0 + k0 + 32);
      vb1 = *(const u16x8*)(pb1 + k0 + 32);
    }
    bf16x8 af[4], bf[4];
#pragma unroll
    for (int i = 0; i < 4; i++) af[i] = ld_frag(&As[(wr + i * 16 + lr) * LSTR + lk]);
#pragma unroll
    for (int j = 0; j < 4; j++) bf[j] = ld_frag(&Bs[(wc + j * 16 + lr) * LSTR + lk]);
#pragma unroll
    for (int i = 0; i < 4; i++)
#pragma unroll
      for (int j = 0; j < 4; j++)
        acc[i][j] = __builtin_amdgcn_mfma_f32_16x16x32_bf16(af[i], bf[j], acc[i][j], 0, 0, 0);
    __syncthreads();
  }
  if (MODE == 0 || (n0 & 255) < 128) {
#pragma unroll
    for (int i = 0; i < 4; i++)
#pragma unroll
      for (int j = 0; j < 4; j++) {
        int row = m0 + wr + i * 16 + (l >> 4) * 4;
        int col = n0 + wc + j * 16 + lr;
#pragma unroll
        for (int r = 0; r < 4; r++)
          C0[(size_t)(row + r) * N + col] = f2bf(acc[i][j][r]);
      }
  } else {
#pragma unroll
    for (int i = 0; i < 4; i++)
#pragma unroll
      for (int j = 0; j < 4; j++) {
        int row = m0 + wr + i * 16 + (l >> 4) * 4;
        int col = n0 + wc + j * 16 + lr;
        int bb = row >> 11, srow = row & 2047;
        int hh2 = col >> 8, d = col & 127;
        u16x4 pk = { f2bf(acc[i][j][0]), f2bf(acc[i][j][1]),
                     f2bf(acc[i][j][2]), f2bf(acc[i][j][3]) };
        *(u16x4*)&C1[((size_t)(bb * 16 + hh2) * 128 + d) * 2048 + srow] = pk;
      }
  }
}

// ------- merged up-projections: kv_up (1024 blocks, K->Ckv V->VT) + q_up (768 blocks) -------
__global__ __launch_bounds__(256) void k_ups(const u16* __restrict__ ckvn, const u16* __restrict__ WkvuT,
                                             u16* __restrict__ Ckv, u16* __restrict__ VTb,
                                             const u16* __restrict__ cqn, const u16* __restrict__ WquT,
                                             u16* __restrict__ qproj) {
  __shared__ u16 As[128 * 40], Bs[128 * 40];
  int id = blockIdx.x, tid = threadIdx.x;
  if (id < 1024) {
    int swzb = (id & 7) * 128 + (id >> 3);
    gemm128_body<1>((swzb >> 5) * 128, (swzb & 31) * 128, ckvn, WkvuT, Ckv, VTb, 4096, 32, tid, As, Bs);
  } else {
    int lin = id - 1024;
    int swzb = (lin & 7) * 96 + (lin >> 3);
    gemm128_body<0>((swzb / 24) * 128, (swzb % 24) * 128, cqn, WquT, qproj, nullptr, 3072, 256, tid, As, Bs);
  }
}

// ---------------- GEMM 64(M)x128(N) tile, f32 out (out-projection) ----------------
__global__ __launch_bounds__(256) void k_gemmh(const u16* __restrict__ A, const u16* __restrict__ Bt,
                                               float* __restrict__ Cv, int M, int N, int K) {
  constexpr int LSTR = 40;
  __shared__ u16 As[64 * LSTR], Bs[128 * LSTR];
  const int tid = threadIdx.x, l = tid & 63, w = tid >> 6;
  const int nwg = gridDim.x * gridDim.y;
  const int lin = blockIdx.y * gridDim.x + blockIdx.x;
  const int swzb = (lin & 7) * (nwg >> 3) + (lin >> 3);
  const int m0 = (swzb / gridDim.x) * 64, n0 = (swzb % gridDim.x) * 128;
  const int wr = (w >> 1) * 32, wc = (w & 1) * 64;
  const int lr = l & 15, lk = (l >> 4) * 8;
  const int sr = tid >> 2, sc = (tid & 3) * 8;
  f32x4 acc[2][4] = {};
  const u16* pa0 = A + (size_t)(m0 + sr) * K + sc;
  const u16* pb0 = Bt + (size_t)(n0 + sr) * K + sc;
  const u16* pb1 = Bt + (size_t)(n0 + 64 + sr) * K + sc;
  u16x8 va0 = *(const u16x8*)pa0;
  u16x8 vb0 = *(const u16x8*)pb0, vb1 = *(const u16x8*)pb1;
  for (int k0 = 0; k0 < K; k0 += 32) {
    *(u16x8*)&As[sr * LSTR + sc] = va0;
    *(u16x8*)&Bs[sr * LSTR + sc] = vb0;
    *(u16x8*)&Bs[(64 + sr) * LSTR + sc] = vb1;
    __syncthreads();
    if (k0 + 32 < K) {
      va0 = *(const u16x8*)(pa0 + k0 + 32);
      vb0 = *(const u16x8*)(pb0 + k0 + 32);
      vb1 = *(const u16x8*)(pb1 + k0 + 32);
    }
    bf16x8 af[2], bf[4];
#pragma unroll
    for (int i = 0; i < 2; i++) af[i] = ld_frag(&As[(wr + i * 16 + lr) * LSTR + lk]);
#pragma unroll
    for (int j = 0; j < 4; j++) bf[j] = ld_frag(&Bs[(wc + j * 16 + lr) * LSTR + lk]);
#pragma unroll
    for (int i = 0; i < 2; i++)
#pragma unroll
      for (int j = 0; j < 4; j++)
        acc[i][j] = __builtin_amdgcn_mfma_f32_16x16x32_bf16(af[i], bf[j], acc[i][j], 0, 0, 0);
    __syncthreads();
  }
#pragma unroll
  for (int i = 0; i < 2; i++)
#pragma unroll
    for (int j = 0; j < 4; j++) {
      int row = m0 + wr + i * 16 + (l >> 4) * 4;
      int col = n0 + wc + j * 16 + lr;
#pragma unroll
      for (int r = 0; r < 4; r++)
        Cv[(size_t)(row + r) * N + col] = acc[i][j][r];
    }
}

// ---- fused attention v14 (= R12 best-measured structure) + fused Q-rope ----
// KVBLK=64, single-buffer 40KB LDS, swapped-QK, in-reg P via cvt_pk + 16 shfls.
__global__ __launch_bounds__(512, 2) void k_attn(const u16* __restrict__ Qp, const u16* __restrict__ Ckv,
                                                 const u16* __restrict__ kropeb, const u16* __restrict__ VT,
                                                 const int* __restrict__ qpos, u16* __restrict__ AO) {
  __shared__ u16 Ks[64 * 192];   // 24KB, XOR-swizzled
  __shared__ u16 Vs[128 * 64];   // 16KB, d-major, XOR-swizzled
  const int tid = threadIdx.x, l = tid & 63, w = tid >> 6;
  const int lr = l & 15, g = l >> 4, lk = g * 8;
  const int bid = blockIdx.x, bh = bid & 31, qt = bid >> 5;  // bh%8 fixes XCD for K/V L2 reuse
  const int b = bh >> 4, hh = bh & 15;
  const int m0 = qt * 128;
  const u32 swz = (u32)(lr & 7) << 3;

  // Q fragments (B-operand) with FUSED ROPE (validated in R13): wave w owns rows m0+w*16..+15
  bf16x8 qa[6];
  {
    const int rowi = b * 2048 + m0 + w * 16 + lr;
    const u16* qrow = Qp + (size_t)rowi * 3072 + hh * 192;
#pragma unroll
    for (int kk = 0; kk < 4; kk++) qa[kk] = ld_frag(qrow + kk * 32 + lk);
    u16x8 e0 = *(const u16x8*)(qrow + 128 + 16 * g);
    u16x8 e1 = *(const u16x8*)(qrow + 136 + 16 * g);
    float fpos = (float)qpos[rowi];
    u16x8 r4, r5;
#pragma unroll
    for (int i = 0; i < 8; i++) {
      float invf = __expf(-(LOG10000 / 32.f) * (float)(8 * g + i));
      float ang = fpos * invf;
      float c = cosf(ang), s = sinf(ang);
      float ev = bf2f(i < 4 ? e0[2 * i] : e1[2 * i - 8]);
      float od = bf2f(i < 4 ? e0[2 * i + 1] : e1[2 * i - 7]);
      r4[i] = f2bf(ev * c - od * s);
      r5[i] = f2bf(od * c + ev * s);
    }
    qa[4] = __builtin_bit_cast(bf16x8, r4);
    qa[5] = __builtin_bit_cast(bf16x8, r5);
  }

  // staging: K = 64x192 (3 chunks/thread @512), V = 128x64 d-major (2 chunks/thread)
  const u16* kptr[3]; int kstep[3]; u32 klds[3];
#pragma unroll
  for (int p = 0; p < 3; p++) {
    int c2 = tid + p * 512;
    int r = c2 / 24, cc = c2 - r * 24;
    klds[p] = (u32)(r * 192 + cc * 8) ^ ((u32)(r & 7) << 3);
    if (cc < 16) { kptr[p] = Ckv + ((size_t)(b * 2048 + r)) * 4096 + hh * 256 + cc * 8; kstep[p] = 64 * 4096; }
    else         { kptr[p] = kropeb + ((size_t)(b * 2048 + r)) * 64 + (cc - 16) * 8;    kstep[p] = 64 * 64; }
  }
  const u16* vptr[2]; u32 vlds[2];
#pragma unroll
  for (int p = 0; p < 2; p++) {
    int c2 = tid + p * 512;
    int d = c2 >> 3, cc = c2 & 7;
    vlds[p] = (u32)(d * 64 + cc * 8) ^ ((u32)(d & 7) << 3);
    vptr[p] = VT + ((size_t)bh * 128 + d) * 2048 + cc * 8;
  }
  u16x8 kreg[3], vreg[2];
#pragma unroll
  for (int p = 0; p < 3; p++) { kreg[p] = *(const u16x8*)kptr[p]; kptr[p] += kstep[p]; }
#pragma unroll
  for (int p = 0; p < 2; p++) { vreg[p] = *(const u16x8*)vptr[p]; vptr[p] += 64; }

  f32x4 oacc[8] = {};
  float lsum = 0.f;
  const int srcA = lr + ((l & 16) << 1);
  const int srcB = srcA + 16;
  const bool hi = (l & 32) != 0;

  for (int t = 0; t < 32; t++) {
#pragma unroll
    for (int p = 0; p < 3; p++) *(u16x8*)&Ks[klds[p]] = kreg[p];
#pragma unroll
    for (int p = 0; p < 2; p++) *(u16x8*)&Vs[vlds[p]] = vreg[p];
    __syncthreads();
    if (t + 1 < 32) {
#pragma unroll
      for (int p = 0; p < 3; p++) { kreg[p] = *(const u16x8*)kptr[p]; kptr[p] += kstep[p]; }
#pragma unroll
      for (int p = 0; p < 2; p++) { vreg[p] = *(const u16x8*)vptr[p]; vptr[p] += 64; }
    }
    // S^T = K * Q^T: lane holds q=lr, kv=16n+4g+r
    f32x4 sacc[4] = {};
    __builtin_amdgcn_s_setprio(1);
#pragma unroll
    for (int n = 0; n < 4; n++)
#pragma unroll
      for (int kk = 0; kk < 6; kk++)
        sacc[n] = __builtin_amdgcn_mfma_f32_16x16x32_bf16(
            ld_frag(&Ks[(u32)((n * 16 + lr) * 192 + kk * 32 + lk) ^ swz]), qa[kk], sacc[n], 0, 0, 0);
    __builtin_amdgcn_s_setprio(0);
    // P = exp(S): per-lane (one q-row); pack via native casts -> v_cvt_pk_bf16_f32
    u32 pw[4][2];
#pragma unroll
    for (int n = 0; n < 4; n++) {
      float p0 = __expf(sacc[n][0]), p1 = __expf(sacc[n][1]),
            p2 = __expf(sacc[n][2]), p3 = __expf(sacc[n][3]);
      lsum += (p0 + p1) + (p2 + p3);
      bf16x2 a01 = { (__bf16)p0, (__bf16)p1 };
      bf16x2 a23 = { (__bf16)p2, (__bf16)p3 };
      pw[n][0] = __builtin_bit_cast(u32, a01);
      pw[n][1] = __builtin_bit_cast(u32, a23);
    }
    // redistribute P to PV A-fragment layout (16 bpermutes, no LDS buffer)
    u32 pa32[2][4];
#pragma unroll
    for (int kk2 = 0; kk2 < 2; kk2++) {
      u32 t0a = __shfl(pw[2 * kk2][0], srcA), t1a = __shfl(pw[2 * kk2 + 1][0], srcA);
      u32 t0b = __shfl(pw[2 * kk2][1], srcA), t1b = __shfl(pw[2 * kk2 + 1][1], srcA);
      u32 t0c = __shfl(pw[2 * kk2][0], srcB), t1c = __shfl(pw[2 * kk2 + 1][0], srcB);
      u32 t0d = __shfl(pw[2 * kk2][1], srcB), t1d = __shfl(pw[2 * kk2 + 1][1], srcB);
      pa32[kk2][0] = hi ? t1a : t0a;
      pa32[kk2][1] = hi ? t1b : t0b;
      pa32[kk2][2] = hi ? t1c : t0c;
      pa32[kk2][3] = hi ? t1d : t0d;
    }
    // O += P * V
    __builtin_amdgcn_s_setprio(1);
#pragma unroll
    for (int kk2 = 0; kk2 < 2; kk2++) {
      u32x4 pv = { pa32[kk2][0], pa32[kk2][1], pa32[kk2][2], pa32[kk2][3] };
      bf16x8 paf = __builtin_bit_cast(bf16x8, pv);
#pragma unroll
      for (int n2 = 0; n2 < 8; n2++)
        oacc[n2] = __builtin_amdgcn_mfma_f32_16x16x32_bf16(
            paf, ld_frag(&Vs[(u32)((n2 * 16 + lr) * 64 + kk2 * 32 + lk) ^ swz]), oacc[n2], 0, 0, 0);
    }
    __builtin_amdgcn_s_setprio(0);
    __syncthreads();
  }
  // epilogue: lsum per q=lr; sum the 4 g-groups, redistribute to rows 4g+r
  float s = lsum;
  s += __shfl_xor(s, 16);
  s += __shfl_xor(s, 32);
  float rl = 1.f / s;
  float rlv[4];
#pragma unroll
  for (int r = 0; r < 4; r++) rlv[r] = __shfl(rl, g * 4 + r);
#pragma unroll
  for (int n2 = 0; n2 < 8; n2++)
#pragma unroll
    for (int r = 0; r < 4; r++) {
      int row = m0 + w * 16 + g * 4 + r;
      AO[((size_t)(b * 2048 + row) * 16 + hh) * 128 + n2 * 16 + lr] = f2bf(oacc[n2][r] * rlv[r]);
    }
}

extern "C" void kernel_launch(void* const* d_in, const int* in_sizes, int n_in,
                              void* d_out, int out_size, void* d_ws, size_t ws_size,
                              hipStream_t stream) {
  const float* q_in  = (const float*)d_in[0];
  const float* kv_in = (const float*)d_in[1];
  const int*   qpos  = (const int*)d_in[2];
  const int*   kpos  = (const int*)d_in[3];
  const float* Wqd   = (const float*)d_in[4];
  const float* qnw   = (const float*)d_in[5];
  const float* Wqu   = (const float*)d_in[6];
  const float* Wkvd  = (const float*)d_in[7];
  const float* kvnw  = (const float*)d_in[8];
  const float* Wkvu  = (const float*)d_in[9];
  const float* Wo    = (const float*)d_in[10];
  float* out = (float*)d_out;
  char* ws = (char*)d_ws;
  size_t off = 0;
  auto alloc = [&](size_t bytes) -> void* {
    void* p = ws + off; off += (bytes + 255) & ~(size_t)255; return p;
  };
  u16*   WqdT   = (u16*)alloc(256ull * 1024 * 2);
  u16*   WquT   = (u16*)alloc(3072ull * 256 * 2);
  u16*   WkvdT  = (u16*)alloc(128ull * 1024 * 2);
  u16*   WkvuT  = (u16*)alloc(4096ull * 32 * 2);
  u16*   WoT    = (u16*)alloc(1024ull * 2048 * 2);
  float* ckvf   = (float*)alloc(4096ull * 128 * 4);
  u16*   ckvn   = (u16*)alloc(4096ull * 32 * 2);
  u16*   kropeb = (u16*)alloc(4096ull * 64 * 2);
  u16*   Ckv    = (u16*)alloc(4096ull * 4096 * 2);
  u16*   VTb    = (u16*)alloc(32ull * 128 * 2048 * 2);
  float* cq     = (float*)alloc(4096ull * 256 * 4);
  u16*   cqn    = (u16*)alloc(4096ull * 256 * 2);
  u16*   qproj  = (u16*)alloc(4096ull * 3072 * 2);
  u16*   AOb    = (u16*)alloc(4096ull * 2048 * 2);
  (void)in_sizes; (void)n_in; (void)out_size; (void)ws_size;

  // 1: all 5 weight transposes
  k_wtrans5<<<3328, 256, 0, stream>>>(Wqd, Wqu, Wkvd, Wkvu, Wo, WqdT, WquT, WkvdT, WkvuT, WoT);
  // 2: both down-projections (f32-A, fused cvt)
  k_downs<<<384, 256, 0, stream>>>(q_in, kv_in, WqdT, WkvdT, cq, ckvf);
  // 3: both norms
  k_norms<<<2048, 256, 0, stream>>>(ckvf, kvnw, kpos, ckvn, kropeb, cq, qnw, cqn, 0.07216878364870322f);
  // 4: both up-projections (kv_up: K->Ckv + V->VT; q_up)
  k_ups<<<1792, 256, 0, stream>>>(ckvn, WkvuT, Ckv, VTb, cqn, WquT, qproj);
  // 5: attention (KVBLK=64 R12 structure + fused q-rope; k_qrope eliminated)
  k_attn<<<512, 512, 0, stream>>>(qproj, Ckv, kropeb, VTb, qpos, AOb);
  // 6: output projection
  k_gemmh<<<dim3(8, 64), 256, 0, stream>>>(AOb, WoT, out, 4096, 1024, 2048);
}